// Round 3
// baseline (39.865 us; speedup 1.0000x reference)
//
#include <hip/hip_runtime.h>

// ParallelCheby2D — real-part-only output (out_size == B*T, verified R2).
// out[b,t] = Re( sum_{i=0..3} x[b,t-i] * g_i(t) ),
//   g_i = sum_{j=0..3} C_i^T (W_r + i W_i)_{4i+j} C_j,  C_d[q] = T_q(|x[t-d]|).
//
// Structure: folded accumulation — per (i,j,p): 8-term row dot for wr and wi,
// then one fold-FMA each into gr[i]/gi[i]. Only 8 persistent accumulators,
// float4 weight loads (1 load : 9 FMA), ~23KB unrolled body (fits 32KB L1I).

static constexpr int T_LEN = 131072;  // 2^17

__global__ __launch_bounds__(256, 4) void cheby2d_kernel(
    const float* __restrict__ xr_g, const float* __restrict__ xi_g,
    const float4* __restrict__ wr4, const float4* __restrict__ wi4,
    float* __restrict__ out)
{
    const int idx = blockIdx.x * 256 + threadIdx.x;
    const int t = idx & (T_LEN - 1);

    // Delayed taps (zero-padded per batch row), magnitudes, Chebyshev rows.
    float xr[4], xi[4];
    float C[4][8];
#pragma unroll
    for (int d = 0; d < 4; ++d) {
        float a = 0.f, b = 0.f;
        if (t >= d) { a = xr_g[idx - d]; b = xi_g[idx - d]; }
        xr[d] = a; xi[d] = b;
        const float r = sqrtf(fmaf(a, a, b * b));
        C[d][0] = 1.f;
        C[d][1] = r;
        const float r2 = r + r;
#pragma unroll
        for (int q = 2; q < 8; ++q)
            C[d][q] = fmaf(r2, C[d][q - 1], -C[d][q - 2]);
    }

    float gr[4], gi[4];
#pragma unroll
    for (int i = 0; i < 4; ++i) { gr[i] = 0.f; gi[i] = 0.f; }

#pragma unroll
    for (int i = 0; i < 4; ++i) {
#pragma unroll
        for (int j = 0; j < 4; ++j) {
            const int blk = ((i << 2) + j) << 4;  // float4 units: 16 per 8x8 block
#pragma unroll
            for (int p = 0; p < 8; ++p) {
                const float4 wa = wr4[blk + (p << 1)];
                const float4 wb = wr4[blk + (p << 1) + 1];
                const float4 va = wi4[blk + (p << 1)];
                const float4 vb = wi4[blk + (p << 1) + 1];

                float tr = wa.x * C[j][0];
                tr = fmaf(wa.y, C[j][1], tr);
                tr = fmaf(wa.z, C[j][2], tr);
                tr = fmaf(wa.w, C[j][3], tr);
                tr = fmaf(wb.x, C[j][4], tr);
                tr = fmaf(wb.y, C[j][5], tr);
                tr = fmaf(wb.z, C[j][6], tr);
                tr = fmaf(wb.w, C[j][7], tr);

                float ti = va.x * C[j][0];
                ti = fmaf(va.y, C[j][1], ti);
                ti = fmaf(va.z, C[j][2], ti);
                ti = fmaf(va.w, C[j][3], ti);
                ti = fmaf(vb.x, C[j][4], ti);
                ti = fmaf(vb.y, C[j][5], ti);
                ti = fmaf(vb.z, C[j][6], ti);
                ti = fmaf(vb.w, C[j][7], ti);

                gr[i] = fmaf(C[i][p], tr, gr[i]);
                gi[i] = fmaf(C[i][p], ti, gi[i]);
            }
        }
    }

    // real(out) = sum_i [ xr_i * gr_i - xi_i * gi_i ]
    float o = 0.f;
#pragma unroll
    for (int i = 0; i < 4; ++i) {
        o = fmaf(xr[i], gr[i], o);
        o = fmaf(-xi[i], gi[i], o);
    }
    out[idx] = o;
}

extern "C" void kernel_launch(void* const* d_in, const int* in_sizes, int n_in,
                              void* d_out, int out_size, void* d_ws, size_t ws_size,
                              hipStream_t stream) {
    const float* xr = (const float*)d_in[0];     // [B,1,T] float32
    const float* xi = (const float*)d_in[1];     // [B,1,T] float32
    const float4* wr = (const float4*)d_in[2];   // [16,8,8] float32
    const float4* wi = (const float4*)d_in[3];   // [16,8,8] float32
    float* out = (float*)d_out;                  // [B,T] real part, float32

    const int total = in_sizes[0];               // B*T = 524288
    const int blocks = total / 256;              // exact: 2048
    cheby2d_kernel<<<blocks, 256, 0, stream>>>(xr, xi, wr, wi, out);
}

// Round 5
// 36.671 us; speedup vs baseline: 1.0871x; 1.0871x over previous
//
#include <hip/hip_runtime.h>
#include <hip/hip_bf16.h>

// ParallelCheby2D via MFMA, layout-robust formulation.
// out[b,t] = Re( sum_i x[t-i] * g_i ),  g_i = sum_j C_i^T W_{4i+j} C_j,
//   C_d[q] = T_q(|x[t-d]|).
// Heavy part: U = M x Y per component, M[8i+p][8j+q] = w[4i+j][p][q] (32x32),
// Y[8j+q][s] = T_q(|x_s[t-j]|).  K=32 split into two v_mfma_f32_32x32x16_bf16.
//
// Layout-robustness: both A and B slots (step s, half hi, elem e) are filled
// with the SAME feature index f = 8*(2s+hi)+e, so the contraction is correct
// under ANY hardware k-mapping (A/B operand mappings are identical on CDNA).
// 32 samples per wave-round (sample = lane&31); lane-half hi supplies Cheby
// rows j=hi (step0) and j=2+hi (step1) locally -> NO cross-lane fragment
// assembly. Only cross-lane op: one __shfl_xor(o,32) combining p-halves.
// D layout (HW-measured m74/m101): col=lane&31, row=(reg&3)+8*(reg>>2)+4*hi.
// Output contract (verified R2): out_size == B*T, real part only, float32.

typedef __attribute__((ext_vector_type(8))) short bf16x8;   // 8 bf16 = 4 VGPRs
typedef __attribute__((ext_vector_type(16))) float f32x16;  // 16 f32 accum

static constexpr int T_LEN  = 131072;  // 2^17
static constexpr int ROUNDS = 4;       // 32 samples per wave per round

union FragU { short s[8]; bf16x8 v; };

__device__ inline short f2bf(float f) {
    union { __hip_bfloat16 h; unsigned short u; } cv;
    cv.h = __float2bfloat16(f);   // RNE
    return (short)cv.u;
}

__global__ __launch_bounds__(256, 2) void cheby2d_mfma(
    const float* __restrict__ xr_g, const float* __restrict__ xi_g,
    const float* __restrict__ wr_g, const float* __restrict__ wi_g,
    float* __restrict__ out)
{
    const int lane = threadIdx.x & 63;
    const int gwid = (blockIdx.x * 256 + threadIdx.x) >> 6;  // global wave id
    const int col  = lane & 31;   // sample slot / A row (8i+p)
    const int hi   = lane >> 5;   // lane half -> k-half slot AND Cheby row owner
    const int row  = col;

    // ---- A fragments (constant weights), once per wave ----
    // slot (s,hi,e) <- M[row][f=8*(2s+hi)+e] = w[4*(row>>3)+(2s+hi)][row&7][e]
    bf16x8 aR[2], aI[2];
#pragma unroll
    for (int s = 0; s < 2; ++s) {
        const int br = 4 * (row >> 3) + 2 * s + hi;
        const float* pr = wr_g + br * 64 + (row & 7) * 8;
        const float* pi = wi_g + br * 64 + (row & 7) * 8;
        FragU fr, fi;
#pragma unroll
        for (int e = 0; e < 8; ++e) { fr.s[e] = f2bf(pr[e]); fi.s[e] = f2bf(pi[e]); }
        aR[s] = fr.v; aI[s] = fi.v;
    }

    // Persistent zero tile as C-in of each chain head (no per-round zeroing).
    f32x16 zacc;
#pragma unroll
    for (int r = 0; r < 16; ++r) zacc[r] = 0.f;

#pragma unroll
    for (int rd = 0; rd < ROUNDS; ++rd) {
        const int idx = gwid * (32 * ROUNDS) + rd * 32 + col;
        const int t   = idx & (T_LEN - 1);

        // ---- taps, magnitudes, Chebyshev rows (f32) ----
        float xr[4], xi[4], C[4][8];
#pragma unroll
        for (int d = 0; d < 4; ++d) {
            float a = 0.f, b = 0.f;
            if (t >= d) { a = xr_g[idx - d]; b = xi_g[idx - d]; }
            xr[d] = a; xi[d] = b;
            const float r = sqrtf(fmaf(a, a, b * b));
            C[d][0] = 1.f;
            C[d][1] = r;
            const float r2 = r + r;
#pragma unroll
            for (int q = 2; q < 8; ++q)
                C[d][q] = fmaf(r2, C[d][q - 1], -C[d][q - 2]);
        }

        // ---- B fragments, purely lane-local ----
        // step0 slot e <- C[hi][e]  (f = 8*hi+e)
        // step1 slot e <- C[2+hi][e] (f = 8*(2+hi)+e)
        // (ternary on hi -> v_cndmask; indices stay compile-time, rule #20)
        FragU b0, b1;
#pragma unroll
        for (int e = 0; e < 8; ++e) {
            b0.s[e] = f2bf(hi ? C[1][e] : C[0][e]);
            b1.s[e] = f2bf(hi ? C[3][e] : C[2][e]);
        }

        // ---- U = M x Y, both components ----
        f32x16 accR = __builtin_amdgcn_mfma_f32_32x32x16_bf16(aR[0], b0.v, zacc, 0, 0, 0);
        accR        = __builtin_amdgcn_mfma_f32_32x32x16_bf16(aR[1], b1.v, accR, 0, 0, 0);
        f32x16 accI = __builtin_amdgcn_mfma_f32_32x32x16_bf16(aI[0], b0.v, zacc, 0, 0, 0);
        accI        = __builtin_amdgcn_mfma_f32_32x32x16_bf16(aI[1], b1.v, accI, 0, 0, 0);

        // ---- epilogue ----
        // acc[4i+r] holds U[i][p=r+4*hi] for sample col (measured D layout).
        // o_half = sum_i ( xr_i * sum_r C[i][4hi+r]*UR - xi_i * sum_r C[i][4hi+r]*UI )
        float o = 0.f;
#pragma unroll
        for (int i = 0; i < 4; ++i) {
            float gr = 0.f, gi = 0.f;
#pragma unroll
            for (int r = 0; r < 4; ++r) {
                const float cip = hi ? C[i][4 + r] : C[i][r];
                gr = fmaf(cip, accR[4 * i + r], gr);
                gi = fmaf(cip, accI[4 * i + r], gi);
            }
            o = fmaf(xr[i], gr, o);
            o = fmaf(-xi[i], gi, o);
        }

        // Combine the two p-halves (partner lane l^32), store from low half.
        o += __shfl_xor(o, 32);
        if (hi == 0) out[idx] = o;
    }
}

extern "C" void kernel_launch(void* const* d_in, const int* in_sizes, int n_in,
                              void* d_out, int out_size, void* d_ws, size_t ws_size,
                              hipStream_t stream) {
    const float* xr = (const float*)d_in[0];  // [B,1,T] float32
    const float* xi = (const float*)d_in[1];  // [B,1,T] float32
    const float* wr = (const float*)d_in[2];  // [16,8,8] float32
    const float* wi = (const float*)d_in[3];  // [16,8,8] float32
    float* out = (float*)d_out;               // [B,T] real part, float32

    const int total = in_sizes[0];            // 524288
    // per block: 4 waves x ROUNDS x 32 samples = 512 samples
    const int blocks = total / (4 * ROUNDS * 32);   // 1024
    cheby2d_mfma<<<blocks, 256, 0, stream>>>(xr, xi, wr, wi, out);
}